// Round 5
// baseline (56.772 us; speedup 1.0000x reference)
//
#include <hip/hip_runtime.h>

#define PY 7
#define PX 7
#define PZ 3
#define S_BINS 147      // 7*7*3
#define C_CH   48
#define PER_ROI 7056    // 48*147
#define CPT 12          // channels per thread
#define QPR 49          // (ybin,xbin) bins per roi
#define TPR 196         // threads per roi = QPR * (48/CPT)

typedef float vf2 __attribute__((ext_vector_type(2)));
typedef float vf4 __attribute__((ext_vector_type(4)));

__global__ __launch_bounds__(256) void roialign3d_kernel(
    const float* __restrict__ fm0, const float* __restrict__ fm1,
    const float* __restrict__ fm2, const float* __restrict__ fm3,
    const float* __restrict__ rois, float* __restrict__ out, int total)
{
    int t = blockIdx.x * blockDim.x + threadIdx.x;
    if (t >= total) return;

    unsigned n  = (unsigned)t / TPR;
    unsigned r2 = (unsigned)t - n * TPR;
    unsigned cs = r2 / QPR;            // channel chunk 0..3
    unsigned q  = r2 - cs * QPR;       // 0..48
    unsigned ybin = q / PX;
    unsigned xbin = q - ybin * PX;

    const float* r = rois + n * 7;
    float by1 = r[0], bx1 = r[1], by2 = r[2], bx2 = r[3], bz1 = r[4], bz2 = r[5];
    int b = (int)r[6];

    // level from normalized h,w; jnp.round = round-half-even = rintf
    float h = by2 - by1, w = bx2 - bx1;
    float lv = rintf(4.0f + 0.5f * log2f(h * w));
    lv = fminf(fmaxf(lv, 0.0f), 3.0f);
    int level = (int)lv;

    const float* fm; int Y, X, Z;
    switch (level) {
        case 0: fm = fm0; Y = 96; X = 96; Z = 48; break;
        case 1: fm = fm1; Y = 48; X = 48; Z = 24; break;
        case 2: fm = fm2; Y = 24; X = 24; Z = 12; break;
        default: fm = fm3; Y = 12; X = 12; Z = 6;  break;
    }

    // ---- y,x geometry (per thread) ----
    float fy1 = by1 * Y, fy2 = by2 * Y;
    float fx1 = bx1 * X, fx2 = bx2 * X;
    float yy = fy1 + (ybin + 0.5f) * (fy2 - fy1) * (1.0f / PY);
    float xx = fx1 + (xbin + 0.5f) * (fx2 - fx1) * (1.0f / PX);

    bool vy = (yy > -1.0f) && (yy < (float)Y);
    bool vx = (xx > -1.0f) && (xx < (float)X);
    float xyv = (vy && vx) ? 1.0f : 0.0f;

    float yc = fminf(fmaxf(yy, 0.0f), (float)(Y - 1));
    float xc = fminf(fmaxf(xx, 0.0f), (float)(X - 1));
    int y0 = (int)floorf(yc);
    int x0 = (int)floorf(xc);
    int y1i = min(y0 + 1, Y - 1);
    int x1i = min(x0 + 1, X - 1);
    float ly = yc - (float)y0, lx = xc - (float)x0;
    float hy = 1.0f - ly,      hx = 1.0f - lx;

    float w00 = hy * hx * xyv, w01 = hy * lx * xyv;
    float w10 = ly * hx * xyv, w11 = ly * lx * xyv;

    // ---- z geometry: 3 bins, per-roi uniform ----
    float fz1 = bz1 * Z, fz2 = bz2 * Z;
    float bsz = (fz2 - fz1) * (1.0f / PZ);
    int zb0, zb1, zb2;
    float wlo0, whi0, wlo1, whi1, wlo2, whi2;
    {
        float zz, zc, lz; int z0i, zb; bool vz, shift; float wl, wh;
        #define ZBIN(i, ZB, WL, WH) \
            zz = fz1 + ((i) + 0.5f) * bsz; \
            vz = (zz > -1.0f) && (zz < (float)Z); \
            zc = fminf(fmaxf(zz, 0.0f), (float)(Z - 1)); \
            z0i = (int)floorf(zc); \
            lz = zc - (float)z0i; \
            zb = min(z0i, Z - 2); \
            shift = (zb != z0i); \
            wl = (shift ? 0.0f : (1.0f - lz)); \
            wh = (shift ? 1.0f : lz); \
            if (!vz) { wl = 0.0f; wh = 0.0f; } \
            ZB = zb; WL = wl; WH = wh;
        ZBIN(0, zb0, wlo0, whi0)
        ZBIN(1, zb1, wlo1, whi1)
        ZBIN(2, zb2, wlo2, whi2)
        #undef ZBIN
    }

    const int plane = Y * X * Z;
    const float* base = fm + ((size_t)b * C_CH + cs * CPT) * (size_t)plane;
    const int o00 = (y0  * X + x0 ) * Z;
    const int o01 = (y0  * X + x1i) * Z;
    const int o10 = (y1i * X + x0 ) * Z;
    const int o11 = (y1i * X + x1i) * Z;

    unsigned s = ybin * (PX * PZ) + xbin * PZ;   // z-triple base bin index
    float* op = out + (size_t)n * PER_ROI + (size_t)cs * CPT * S_BINS + s;

    // ---- path select (roi-uniform -> wave-coherent) ----
    int zq = min(zb0, Z - 4);          // float4 @ zq covers zq..zq+3, in-bounds (Z>=6)
    int dA2 = zb2 - zq;
    bool pathA = (dA2 <= 2);

    if (pathA) {
        // one float4 per corner; W is 3x4 built with static indices
        int d0 = zb0 - zq, d1 = zb1 - zq, d2 = zb2 - zq;
        float W0[4], W1[4], W2[4];
        #pragma unroll
        for (int j = 0; j < 4; ++j) {
            W0[j] = (j == d0) ? wlo0 : (j == d0 + 1) ? whi0 : 0.0f;
            W1[j] = (j == d1) ? wlo1 : (j == d1 + 1) ? whi1 : 0.0f;
            W2[j] = (j == d2) ? wlo2 : (j == d2 + 1) ? whi2 : 0.0f;
        }
        const float* p00 = base + o00 + zq;
        const float* p01 = base + o01 + zq;
        const float* p10 = base + o10 + zq;
        const float* p11 = base + o11 + zq;
        #pragma unroll 2
        for (int c = 0; c < CPT; ++c) {
            vf4 r00 = *(const vf4*)p00;
            vf4 r01 = *(const vf4*)p01;
            vf4 r10 = *(const vf4*)p10;
            vf4 r11 = *(const vf4*)p11;
            float rs0 = w00*r00[0] + w01*r01[0] + w10*r10[0] + w11*r11[0];
            float rs1 = w00*r00[1] + w01*r01[1] + w10*r10[1] + w11*r11[1];
            float rs2 = w00*r00[2] + w01*r01[2] + w10*r10[2] + w11*r11[2];
            float rs3 = w00*r00[3] + w01*r01[3] + w10*r10[3] + w11*r11[3];
            __builtin_nontemporal_store(W0[0]*rs0 + W0[1]*rs1 + W0[2]*rs2 + W0[3]*rs3, op + 0);
            __builtin_nontemporal_store(W1[0]*rs0 + W1[1]*rs1 + W1[2]*rs2 + W1[3]*rs3, op + 1);
            __builtin_nontemporal_store(W2[0]*rs0 + W2[1]*rs1 + W2[2]*rs2 + W2[3]*rs3, op + 2);
            p00 += plane; p01 += plane; p10 += plane; p11 += plane;
            op += S_BINS;
        }
        return;
    }

    int zB = zb2 - 2;                   // !pathA => zb2 >= 3 => zB >= 1; covers zb2, zb2+1 in-bounds
    bool d1inA = (zb1 - zq) <= 2;
    bool d1inB = (zb1 >= zB);
    bool pathB = d1inA || d1inB;

    if (pathB) {
        // two float4 per corner: cells 0..3 -> zq+j, cells 4..7 -> zB+(j-4)
        int d0 = zb0 - zq;                          // <= 2
        int d1 = d1inA ? (zb1 - zq) : (4 + zb1 - zB);
        int d2 = 6;
        float W0[8], W1[8], W2[8];
        #pragma unroll
        for (int j = 0; j < 8; ++j) {
            W0[j] = (j == d0) ? wlo0 : (j == d0 + 1) ? whi0 : 0.0f;
            W1[j] = (j == d1) ? wlo1 : (j == d1 + 1) ? whi1 : 0.0f;
            W2[j] = (j == d2) ? wlo2 : (j == d2 + 1) ? whi2 : 0.0f;
        }
        const float* p00 = base + o00; const float* p01 = base + o01;
        const float* p10 = base + o10; const float* p11 = base + o11;
        for (int c = 0; c < CPT; ++c) {
            vf4 a00 = *(const vf4*)(p00 + zq), b00v = *(const vf4*)(p00 + zB);
            vf4 a01 = *(const vf4*)(p01 + zq), b01v = *(const vf4*)(p01 + zB);
            vf4 a10 = *(const vf4*)(p10 + zq), b10v = *(const vf4*)(p10 + zB);
            vf4 a11 = *(const vf4*)(p11 + zq), b11v = *(const vf4*)(p11 + zB);
            float rs[8];
            #pragma unroll
            for (int j = 0; j < 4; ++j) {
                rs[j]     = w00*a00[j] + w01*a01[j] + w10*a10[j] + w11*a11[j];
                rs[4 + j] = w00*b00v[j] + w01*b01v[j] + w10*b10v[j] + w11*b11v[j];
            }
            float v0 = 0.0f, v1 = 0.0f, v2 = 0.0f;
            #pragma unroll
            for (int j = 0; j < 8; ++j) {
                v0 += W0[j] * rs[j]; v1 += W1[j] * rs[j]; v2 += W2[j] * rs[j];
            }
            __builtin_nontemporal_store(v0, op + 0);
            __builtin_nontemporal_store(v1, op + 1);
            __builtin_nontemporal_store(v2, op + 2);
            p00 += plane; p01 += plane; p10 += plane; p11 += plane;
            op += S_BINS;
        }
        return;
    }

    // path C (rare, large z-span): per-bin float2s, R4 math
    {
        const float* p00 = base + o00; const float* p01 = base + o01;
        const float* p10 = base + o10; const float* p11 = base + o11;
        for (int c = 0; c < CPT; ++c) {
            #define BIN(ZB, WL, WH, OFS) { \
                vf2 v00 = *(const vf2*)(p00 + ZB); \
                vf2 v01 = *(const vf2*)(p01 + ZB); \
                vf2 v10 = *(const vf2*)(p10 + ZB); \
                vf2 v11 = *(const vf2*)(p11 + ZB); \
                float lo = w00*v00[0] + w01*v01[0] + w10*v10[0] + w11*v11[0]; \
                float hi = w00*v00[1] + w01*v01[1] + w10*v10[1] + w11*v11[1]; \
                __builtin_nontemporal_store(WL*lo + WH*hi, op + OFS); }
            BIN(zb0, wlo0, whi0, 0)
            BIN(zb1, wlo1, whi1, 1)
            BIN(zb2, wlo2, whi2, 2)
            #undef BIN
            p00 += plane; p01 += plane; p10 += plane; p11 += plane;
            op += S_BINS;
        }
    }
}

extern "C" void kernel_launch(void* const* d_in, const int* in_sizes, int n_in,
                              void* d_out, int out_size, void* d_ws, size_t ws_size,
                              hipStream_t stream) {
    const float* f0   = (const float*)d_in[0];
    const float* f1   = (const float*)d_in[1];
    const float* f2   = (const float*)d_in[2];
    const float* f3   = (const float*)d_in[3];
    const float* rois = (const float*)d_in[4];
    float* out = (float*)d_out;

    int n_rois = out_size / PER_ROI;    // 1200
    int total  = n_rois * TPR;          // 235200
    int block  = 256;
    int grid   = (total + block - 1) / block;
    roialign3d_kernel<<<grid, block, 0, stream>>>(f0, f1, f2, f3, rois, out, total);
}

// Round 6
// 37.086 us; speedup vs baseline: 1.5308x; 1.5308x over previous
//
#include <hip/hip_runtime.h>

#define PY 7
#define PX 7
#define PZ 3
#define S_BINS 147      // 7*7*3
#define C_CH   48
#define PER_ROI 7056    // 48*147
#define NCHUNK 4        // channel chunks per roi
#define CPT    12       // channels per thread (48/NCHUNK)
#define TPR    (S_BINS * NCHUNK)   // 588 threads per roi

// One thread per (roi, channel-chunk, bin); loops over 12 channels.
// Identical gather/store pattern to the R4 winner; 4x the waves for MLP.
__global__ __launch_bounds__(256) void roialign3d_kernel(
    const float* __restrict__ f0, const float* __restrict__ f1,
    const float* __restrict__ f2, const float* __restrict__ f3,
    const float* __restrict__ rois, float* __restrict__ out, int total)
{
    int t = blockIdx.x * blockDim.x + threadIdx.x;
    if (t >= total) return;

    unsigned n   = (unsigned)t / TPR;
    unsigned rem = (unsigned)t - n * TPR;
    unsigned cs  = rem / S_BINS;          // channel chunk 0..3
    unsigned s   = rem - cs * S_BINS;     // bin 0..146 (consecutive in lane)

    const float* r = rois + n * 7;
    float by1 = r[0], bx1 = r[1], by2 = r[2], bx2 = r[3], bz1 = r[4], bz2 = r[5];
    int b = (int)r[6];

    // level from normalized h,w; jnp.round = round-half-even = rintf
    float h = by2 - by1, w = bx2 - bx1;
    float lv = rintf(4.0f + 0.5f * log2f(h * w));
    lv = fminf(fmaxf(lv, 0.0f), 3.0f);
    int level = (int)lv;

    const float* fm; int Y, X, Z;
    switch (level) {
        case 0: fm = f0; Y = 96; X = 96; Z = 48; break;
        case 1: fm = f1; Y = 48; X = 48; Z = 24; break;
        case 2: fm = f2; Y = 24; X = 24; Z = 12; break;
        default: fm = f3; Y = 12; X = 12; Z = 6;  break;
    }

    int ybin = s / (PX * PZ);
    int rs   = s - ybin * (PX * PZ);
    int xbin = rs / PZ;
    int zbin = rs - xbin * PZ;

    float fy1 = by1 * Y, fy2 = by2 * Y;
    float fx1 = bx1 * X, fx2 = bx2 * X;
    float fz1 = bz1 * Z, fz2 = bz2 * Z;

    float yy = fy1 + (ybin + 0.5f) * (fy2 - fy1) * (1.0f / PY);
    float xx = fx1 + (xbin + 0.5f) * (fx2 - fx1) * (1.0f / PX);
    float zz = fz1 + (zbin + 0.5f) * (fz2 - fz1) * (1.0f / PZ);

    bool valid = (yy > -1.0f) && (yy < (float)Y) &&
                 (xx > -1.0f) && (xx < (float)X) &&
                 (zz > -1.0f) && (zz < (float)Z);

    float yc = fminf(fmaxf(yy, 0.0f), (float)(Y - 1));
    float xc = fminf(fmaxf(xx, 0.0f), (float)(X - 1));
    float zc = fminf(fmaxf(zz, 0.0f), (float)(Z - 1));

    int y0 = (int)floorf(yc);
    int x0 = (int)floorf(xc);
    int z0 = (int)floorf(zc);
    int y1i = min(y0 + 1, Y - 1);
    int x1i = min(x0 + 1, X - 1);

    float ly = yc - (float)y0, lx = xc - (float)x0, lz = zc - (float)z0;
    float hy = 1.0f - ly,      hx = 1.0f - lx,      hz = 1.0f - lz;

    // z-pair base covering (zb, zb+1); clamp edge -> weights (0,1)
    int  zb    = min(z0, Z - 2);
    bool shift = (zb != z0);
    float wlo  = shift ? 0.0f : hz;
    float whi  = shift ? 1.0f : lz;
    if (!valid) { wlo = 0.0f; whi = 0.0f; }

    float w00 = hy * hx, w01 = hy * lx, w10 = ly * hx, w11 = ly * lx;

    const int plane = Y * X * Z;
    const float* base = fm + ((size_t)b * C_CH + cs * CPT) * (size_t)plane;

    const float* p00 = base + (y0  * X + x0 ) * Z + zb;
    const float* p01 = base + (y0  * X + x1i) * Z + zb;
    const float* p10 = base + (y1i * X + x0 ) * Z + zb;
    const float* p11 = base + (y1i * X + x1i) * Z + zb;

    float* op = out + (size_t)n * PER_ROI + (size_t)cs * CPT * S_BINS + s;

    #pragma unroll 4
    for (int c = 0; c < CPT; ++c) {
        float2 v00 = *(const float2*)p00;
        float2 v01 = *(const float2*)p01;
        float2 v10 = *(const float2*)p10;
        float2 v11 = *(const float2*)p11;

        float lo = w00 * v00.x + w01 * v01.x + w10 * v10.x + w11 * v11.x;
        float hi = w00 * v00.y + w01 * v01.y + w10 * v10.y + w11 * v11.y;
        float val = wlo * lo + whi * hi;

        __builtin_nontemporal_store(val, op);

        p00 += plane; p01 += plane; p10 += plane; p11 += plane;
        op += S_BINS;
    }
}

extern "C" void kernel_launch(void* const* d_in, const int* in_sizes, int n_in,
                              void* d_out, int out_size, void* d_ws, size_t ws_size,
                              hipStream_t stream) {
    const float* f0   = (const float*)d_in[0];
    const float* f1   = (const float*)d_in[1];
    const float* f2   = (const float*)d_in[2];
    const float* f3   = (const float*)d_in[3];
    const float* rois = (const float*)d_in[4];
    float* out = (float*)d_out;

    int n_rois = out_size / PER_ROI;     // 1200
    int total  = n_rois * TPR;           // 705600
    int block  = 256;
    int grid   = (total + block - 1) / block;
    roialign3d_kernel<<<grid, block, 0, stream>>>(f0, f1, f2, f3, rois, out, total);
}